// Round 3
// baseline (275.967 us; speedup 1.0000x reference)
//
#include <hip/hip_runtime.h>
#include <math.h>

// Problem constants (B=8, F=32 -> 256 frames of 224x224x3 f32)
#define NFRAMES 256
#define NH 224
#define NW 224
#define NPIX (NH * NW)            // 50176
#define NOISE_LEN 766             // 3*L - 2
#define WIN_LEN 511               // 2*L - 1
#define BLOCKS_PER_FRAME (NPIX / 256)  // 196
#define NXCD 8

// ---------------------------------------------------------------------------
// Kernel 1 (unchanged): one block per frame (256 blocks -> one per CU).
// Wave j (4 waves) computes the 511-tap convolution for noise row j at output
// position b: 8 taps per lane in f64, then a 64-lane shuffle reduction.
// Window normalization S via closed-form geometric series (no serial loop).
// Thread 0 composes the 3x3 homography in f64 and writes 9 floats.
// ---------------------------------------------------------------------------
__global__ __launch_bounds__(256) void build_mats_v2(
    const float* __restrict__ noise,   // (4, 766)
    const float* __restrict__ basis,   // (4, 3, 3)
    float* __restrict__ Mout) {        // (256, 9)
  const int b = blockIdx.x;      // frame index
  const int t = threadIdx.x;
  const int j = t >> 6;          // noise row (wave id)
  const int lane = t & 63;

  __shared__ double wsh[WIN_LEN];
  __shared__ double vsh[4];

  // weights w[k] = 1.1^(255 - |k-255|), k = 0..510
  for (int k = t; k < WIN_LEN; k += 256) {
    int e = 255 - abs(k - 255);
    wsh[k] = pow(1.1, (double)e);
  }
  __syncthreads();

  // sum(w) closed form: sum_{e=0}^{254} 1.1^e + sum_{e=0}^{255} 1.1^e
  const double S = (pow(1.1, 255.0) - 1.0) * 10.0 + (pow(1.1, 256.0) - 1.0) * 10.0;

  // conv (valid) at position b for row j: sum_{k=0}^{510} n[j][b+k] * w[k]
  const float* row = noise + j * NOISE_LEN + b;
  const int k0 = lane * 8;
  double acc = 0.0;
  #pragma unroll
  for (int i = 0; i < 8; ++i) {
    const int k = k0 + i;
    if (k < WIN_LEN) acc = fma((double)row[k], wsh[k], acc);
  }
  #pragma unroll
  for (int off = 32; off > 0; off >>= 1) acc += __shfl_down(acc, off, 64);
  if (lane == 0) {
    const double v = acc / S;
    vsh[j] = v > 0.0 ? v : 0.0;   // relu
  }
  __syncthreads();

  if (t == 0) {
    const double wv0 = vsh[0], wv1 = vsh[1], wv2 = vsh[2], wv3 = vsh[3];
    const double swv = wv0 + wv1 + wv2 + wv3;
    double warp[9];
    #pragma unroll
    for (int e = 0; e < 9; ++e) {
      warp[e] = wv0 * (double)basis[0 * 9 + e] + wv1 * (double)basis[1 * 9 + e] +
                wv2 * (double)basis[2 * 9 + e] + wv3 * (double)basis[3 * 9 + e];
    }
    warp[0] += 4.0 - swv;
    warp[4] += 4.0 - swv;
    warp[8] += 4.0 - swv;

    // M = [S(h-1,w-1) @ T(.5,.5)] @ warp @ [T(-.5,-.5) @ S(1/(h-1),1/(w-1))]
    const double W1 = (double)(NW - 1);
    const double H1 = (double)(NH - 1);
    double T[9];
    #pragma unroll
    for (int c = 0; c < 3; ++c) {
      T[0 * 3 + c] = W1 * warp[0 * 3 + c] + 0.5 * W1 * warp[2 * 3 + c];
      T[1 * 3 + c] = H1 * warp[1 * 3 + c] + 0.5 * H1 * warp[2 * 3 + c];
      T[2 * 3 + c] = warp[2 * 3 + c];
    }
    float* Mo = Mout + b * 9;
    #pragma unroll
    for (int r = 0; r < 3; ++r) {
      Mo[r * 3 + 0] = (float)(T[r * 3 + 0] / W1);
      Mo[r * 3 + 1] = (float)(T[r * 3 + 1] / H1);
      Mo[r * 3 + 2] = (float)(-0.5 * T[r * 3 + 0] - 0.5 * T[r * 3 + 1] + T[r * 3 + 2]);
    }
  }
}

// ---------------------------------------------------------------------------
// Kernel 2 (v5): per-pixel projective warp + bilinear sample.
// ISOLATED CHANGE vs r2 (264.0 us): XCD-chunked block swizzle ONLY.
//  Mechanism: a frame (602 KB) fits one XCD's 4 MB L2 and is re-read with
//  ~2x row overlap by its 196 blocks. Default round-robin dispatch puts
//  adjacent strips on different XCDs -> shared input rows replicate into
//  2-3 L2s via L3 round-trips on the gather critical path. Chunked swizzle
//  (50176 = 8*6272, bijective) gives each XCD 32 whole frames -> every
//  input line is fetched into exactly one L2 and reused there.
//  Kept from r2 (proven/neutral): packed dwordx3 corner loads, NT scalar
//  stores (out never re-read; keep L2/L3 for the gather set).
// Validity matches reference: tested on un-clipped float corner coords,
// clip-then-truncate for indices, zero fill outside.
// ---------------------------------------------------------------------------
__global__ __launch_bounds__(256) void warp_bilinear_kernel(
    const float* __restrict__ x,     // (256, 224, 224, 3)
    const float* __restrict__ M,     // (256, 9)
    float* __restrict__ out) {       // (256, 224, 224, 3)
  // hw assigns wg i -> XCD (i % 8); remap so XCD k owns contiguous frames.
  const int CHUNK = (NFRAMES * BLOCKS_PER_FRAME) / NXCD;  // 6272
  const int raw = blockIdx.x;
  const int bid = (raw & (NXCD - 1)) * CHUNK + (raw >> 3);

  const int l = bid / BLOCKS_PER_FRAME;                      // frame (block-uniform)
  const int p = (bid - l * BLOCKS_PER_FRAME) * 256 + threadIdx.x;  // pixel in frame

  const float* Mp = M + l * 9;   // uniform -> scalar loads
  const float m00 = Mp[0], m01 = Mp[1], m02 = Mp[2];
  const float m10 = Mp[3], m11 = Mp[4], m12 = Mp[5];
  const float m20 = Mp[6], m21 = Mp[7], m22 = Mp[8];

  const int r = p / NW;
  const int c = p - r * NW;
  const float cf = (float)c, rf = (float)r;

  const float fx = fmaf(m00, cf, fmaf(m01, rf, m02));
  const float fy = fmaf(m10, cf, fmaf(m11, rf, m12));
  const float fz = fmaf(m20, cf, fmaf(m21, rf, m22));
  const float inv = __builtin_amdgcn_rcpf(fz);   // ~2^-22 rel err, in budget
  const float xs = fx * inv;
  const float ys = fy * inv;

  const float x0f = floorf(xs), y0f = floorf(ys);
  const float wx = xs - x0f, wy = ys - y0f;
  const float x1f = x0f + 1.0f, y1f = y0f + 1.0f;

  const float vx0 = (x0f >= 0.0f && x0f <= (float)(NW - 1)) ? 1.0f : 0.0f;
  const float vx1 = (x1f >= 0.0f && x1f <= (float)(NW - 1)) ? 1.0f : 0.0f;
  const float vy0 = (y0f >= 0.0f && y0f <= (float)(NH - 1)) ? 1.0f : 0.0f;
  const float vy1 = (y1f >= 0.0f && y1f <= (float)(NH - 1)) ? 1.0f : 0.0f;

  const int xi0 = (int)fminf(fmaxf(x0f, 0.0f), (float)(NW - 1));
  const int xi1 = (int)fminf(fmaxf(x1f, 0.0f), (float)(NW - 1));
  const int yi0 = (int)fminf(fmaxf(y0f, 0.0f), (float)(NH - 1));
  const int yi1 = (int)fminf(fmaxf(y1f, 0.0f), (float)(NH - 1));

  const float* img = x + (size_t)l * (NPIX * 3);
  const float* p00 = img + (yi0 * NW + xi0) * 3;
  const float* p01 = img + (yi0 * NW + xi1) * 3;
  const float* p10 = img + (yi1 * NW + xi0) * 3;
  const float* p11 = img + (yi1 * NW + xi1) * 3;

  // Packed 12-B corner fetches -> global_load_dwordx3 each.
  float q00[3], q01[3], q10[3], q11[3];
  __builtin_memcpy(q00, p00, 12);
  __builtin_memcpy(q01, p01, 12);
  __builtin_memcpy(q10, p10, 12);
  __builtin_memcpy(q11, p11, 12);

  const float w00 = (1.0f - wy) * (1.0f - wx) * vy0 * vx0;
  const float w01 = (1.0f - wy) * wx * vy0 * vx1;
  const float w10 = wy * (1.0f - wx) * vy1 * vx0;
  const float w11 = wy * wx * vy1 * vx1;

  const float o0 = w00 * q00[0] + w01 * q01[0] + w10 * q10[0] + w11 * q11[0];
  const float o1 = w00 * q00[1] + w01 * q01[1] + w10 * q10[1] + w11 * q11[1];
  const float o2 = w00 * q00[2] + w01 * q01[2] + w10 * q10[2] + w11 * q11[2];

  // Nontemporal: out is never re-read; keep L2/L3 for the gather set.
  float* op = out + ((size_t)l * NPIX + p) * 3;
  __builtin_nontemporal_store(o0, op + 0);
  __builtin_nontemporal_store(o1, op + 1);
  __builtin_nontemporal_store(o2, op + 2);
}

extern "C" void kernel_launch(void* const* d_in, const int* in_sizes, int n_in,
                              void* d_out, int out_size, void* d_ws, size_t ws_size,
                              hipStream_t stream) {
  (void)in_sizes; (void)n_in; (void)out_size; (void)ws_size;
  const float* x     = (const float*)d_in[0];   // (8,32,224,224,3) f32
  const float* noise = (const float*)d_in[1];   // (4,766) f32
  const float* basis = (const float*)d_in[2];   // (4,3,3) f32
  float* out  = (float*)d_out;
  float* Mbuf = (float*)d_ws;                   // 256*9 floats scratch

  build_mats_v2<<<NFRAMES, 256, 0, stream>>>(noise, basis, Mbuf);
  warp_bilinear_kernel<<<NFRAMES * BLOCKS_PER_FRAME, 256, 0, stream>>>(x, Mbuf, out);
}

// Round 4
// 272.083 us; speedup vs baseline: 1.0143x; 1.0143x over previous
//
#include <hip/hip_runtime.h>
#include <math.h>

// Problem constants (B=8, F=32 -> 256 frames of 224x224x3 f32)
#define NFRAMES 256
#define NH 224
#define NW 224
#define NPIX (NH * NW)            // 50176
#define NOISE_LEN 766             // 3*L - 2
#define WIN_LEN 511               // 2*L - 1
#define PX_PER_THREAD 2
#define PX_PER_BLOCK (256 * PX_PER_THREAD)            // 512
#define BLOCKS_PER_FRAME (NPIX / PX_PER_BLOCK)        // 98

typedef float f32x4 __attribute__((ext_vector_type(4), aligned(4)));
typedef float f32x2 __attribute__((ext_vector_type(2), aligned(4)));

// ---------------------------------------------------------------------------
// Kernel 1 (unchanged): one block per frame (256 blocks -> one per CU).
// ---------------------------------------------------------------------------
__global__ __launch_bounds__(256) void build_mats_v2(
    const float* __restrict__ noise,   // (4, 766)
    const float* __restrict__ basis,   // (4, 3, 3)
    float* __restrict__ Mout) {        // (256, 9)
  const int b = blockIdx.x;      // frame index
  const int t = threadIdx.x;
  const int j = t >> 6;          // noise row (wave id)
  const int lane = t & 63;

  __shared__ double wsh[WIN_LEN];
  __shared__ double vsh[4];

  // weights w[k] = 1.1^(255 - |k-255|), k = 0..510
  for (int k = t; k < WIN_LEN; k += 256) {
    int e = 255 - abs(k - 255);
    wsh[k] = pow(1.1, (double)e);
  }
  __syncthreads();

  // sum(w) closed form: sum_{e=0}^{254} 1.1^e + sum_{e=0}^{255} 1.1^e
  const double S = (pow(1.1, 255.0) - 1.0) * 10.0 + (pow(1.1, 256.0) - 1.0) * 10.0;

  // conv (valid) at position b for row j: sum_{k=0}^{510} n[j][b+k] * w[k]
  const float* row = noise + j * NOISE_LEN + b;
  const int k0 = lane * 8;
  double acc = 0.0;
  #pragma unroll
  for (int i = 0; i < 8; ++i) {
    const int k = k0 + i;
    if (k < WIN_LEN) acc = fma((double)row[k], wsh[k], acc);
  }
  #pragma unroll
  for (int off = 32; off > 0; off >>= 1) acc += __shfl_down(acc, off, 64);
  if (lane == 0) {
    const double v = acc / S;
    vsh[j] = v > 0.0 ? v : 0.0;   // relu
  }
  __syncthreads();

  if (t == 0) {
    const double wv0 = vsh[0], wv1 = vsh[1], wv2 = vsh[2], wv3 = vsh[3];
    const double swv = wv0 + wv1 + wv2 + wv3;
    double warp[9];
    #pragma unroll
    for (int e = 0; e < 9; ++e) {
      warp[e] = wv0 * (double)basis[0 * 9 + e] + wv1 * (double)basis[1 * 9 + e] +
                wv2 * (double)basis[2 * 9 + e] + wv3 * (double)basis[3 * 9 + e];
    }
    warp[0] += 4.0 - swv;
    warp[4] += 4.0 - swv;
    warp[8] += 4.0 - swv;

    // M = [S(h-1,w-1) @ T(.5,.5)] @ warp @ [T(-.5,-.5) @ S(1/(h-1),1/(w-1))]
    const double W1 = (double)(NW - 1);
    const double H1 = (double)(NH - 1);
    double T[9];
    #pragma unroll
    for (int c = 0; c < 3; ++c) {
      T[0 * 3 + c] = W1 * warp[0 * 3 + c] + 0.5 * W1 * warp[2 * 3 + c];
      T[1 * 3 + c] = H1 * warp[1 * 3 + c] + 0.5 * H1 * warp[2 * 3 + c];
      T[2 * 3 + c] = warp[2 * 3 + c];
    }
    float* Mo = Mout + b * 9;
    #pragma unroll
    for (int r = 0; r < 3; ++r) {
      Mo[r * 3 + 0] = (float)(T[r * 3 + 0] / W1);
      Mo[r * 3 + 1] = (float)(T[r * 3 + 1] / H1);
      Mo[r * 3 + 2] = (float)(-0.5 * T[r * 3 + 0] - 0.5 * T[r * 3 + 1] + T[r * 3 + 2]);
    }
  }
}

// ---------------------------------------------------------------------------
// Per-pixel sample: projective warp + bilinear, reference-exact validity
// (un-clipped float corner tests, clip-then-truncate indices, zero outside).
// ---------------------------------------------------------------------------
__device__ __forceinline__ void sample_px(
    const float* __restrict__ img, int p,
    float m00, float m01, float m02, float m10, float m11, float m12,
    float m20, float m21, float m22, float* __restrict__ o) {
  const int r = p / NW;
  const int c = p - r * NW;
  const float cf = (float)c, rf = (float)r;

  const float fx = fmaf(m00, cf, fmaf(m01, rf, m02));
  const float fy = fmaf(m10, cf, fmaf(m11, rf, m12));
  const float fz = fmaf(m20, cf, fmaf(m21, rf, m22));
  const float inv = __builtin_amdgcn_rcpf(fz);   // ~2^-22 rel err, in budget
  const float xs = fx * inv;
  const float ys = fy * inv;

  const float x0f = floorf(xs), y0f = floorf(ys);
  const float wx = xs - x0f, wy = ys - y0f;
  const float x1f = x0f + 1.0f, y1f = y0f + 1.0f;

  const float vx0 = (x0f >= 0.0f && x0f <= (float)(NW - 1)) ? 1.0f : 0.0f;
  const float vx1 = (x1f >= 0.0f && x1f <= (float)(NW - 1)) ? 1.0f : 0.0f;
  const float vy0 = (y0f >= 0.0f && y0f <= (float)(NH - 1)) ? 1.0f : 0.0f;
  const float vy1 = (y1f >= 0.0f && y1f <= (float)(NH - 1)) ? 1.0f : 0.0f;

  const int xi0 = (int)fminf(fmaxf(x0f, 0.0f), (float)(NW - 1));
  const int xi1 = (int)fminf(fmaxf(x1f, 0.0f), (float)(NW - 1));
  const int yi0 = (int)fminf(fmaxf(y0f, 0.0f), (float)(NH - 1));
  const int yi1 = (int)fminf(fmaxf(y1f, 0.0f), (float)(NH - 1));

  const float* p00 = img + (yi0 * NW + xi0) * 3;
  const float* p01 = img + (yi0 * NW + xi1) * 3;
  const float* p10 = img + (yi1 * NW + xi0) * 3;
  const float* p11 = img + (yi1 * NW + xi1) * 3;

  // Packed 12-B corner fetches -> global_load_dwordx3 each.
  float q00[3], q01[3], q10[3], q11[3];
  __builtin_memcpy(q00, p00, 12);
  __builtin_memcpy(q01, p01, 12);
  __builtin_memcpy(q10, p10, 12);
  __builtin_memcpy(q11, p11, 12);

  const float w00 = (1.0f - wy) * (1.0f - wx) * vy0 * vx0;
  const float w01 = (1.0f - wy) * wx * vy0 * vx1;
  const float w10 = wy * (1.0f - wx) * vy1 * vx0;
  const float w11 = wy * wx * vy1 * vx1;

  o[0] = w00 * q00[0] + w01 * q01[0] + w10 * q10[0] + w11 * q11[0];
  o[1] = w00 * q00[1] + w01 * q01[1] + w10 * q10[1] + w11 * q11[1];
  o[2] = w00 * q00[2] + w01 * q01[2] + w10 * q10[2] + w11 * q11[2];
}

// ---------------------------------------------------------------------------
// Kernel 2 (v6): 2 adjacent pixels per thread.
// ISOLATED CHANGE vs r2-best (264.0 us): pixel-pair processing ONLY.
//  Theory: the gather is bound by L1/TA unique-cacheline touches per wave,
//  not VMEM instruction count (r2: 15->5 insts/px was neutral) and not
//  L2/L3 locality (r3: swizzle hurt -12us, retired). Two adjacent output
//  pixels map to source points ~1px apart, so a wave covering 128 px has
//  nearly the same unique-line footprint as one covering 64 px:
//  lines-per-pixel ~1.8x down. Wave count (and per-wave index/scalar
//  overhead) also halves. 8 gathers in flight per thread doubles MLP.
//  Kept: packed dwordx3 corner loads, NT stores (24 B/thread contiguous:
//  dwordx4 + dwordx2, wave stores 3 KB contiguous), no swizzle.
// ---------------------------------------------------------------------------
__global__ __launch_bounds__(256) void warp_bilinear_kernel(
    const float* __restrict__ x,     // (256, 224, 224, 3)
    const float* __restrict__ M,     // (256, 9)
    float* __restrict__ out) {       // (256, 224, 224, 3)
  const int bid = blockIdx.x;
  const int l = bid / BLOCKS_PER_FRAME;                     // frame (block-uniform)
  const int p0 = (bid - l * BLOCKS_PER_FRAME) * PX_PER_BLOCK + threadIdx.x * 2;

  const float* Mp = M + l * 9;   // uniform -> scalar loads
  const float m00 = Mp[0], m01 = Mp[1], m02 = Mp[2];
  const float m10 = Mp[3], m11 = Mp[4], m12 = Mp[5];
  const float m20 = Mp[6], m21 = Mp[7], m22 = Mp[8];

  const float* img = x + (size_t)l * (NPIX * 3);

  float o[6];
  sample_px(img, p0,     m00, m01, m02, m10, m11, m12, m20, m21, m22, o + 0);
  sample_px(img, p0 + 1, m00, m01, m02, m10, m11, m12, m20, m21, m22, o + 3);

  // Nontemporal 24-B store: out is never re-read; keep L2/L3 for gathers.
  float* op = out + ((size_t)l * NPIX + p0) * 3;
  f32x4 v0 = {o[0], o[1], o[2], o[3]};
  f32x2 v1 = {o[4], o[5]};
  __builtin_nontemporal_store(v0, (f32x4*)op);
  __builtin_nontemporal_store(v1, (f32x2*)(op + 4));
}

extern "C" void kernel_launch(void* const* d_in, const int* in_sizes, int n_in,
                              void* d_out, int out_size, void* d_ws, size_t ws_size,
                              hipStream_t stream) {
  (void)in_sizes; (void)n_in; (void)out_size; (void)ws_size;
  const float* x     = (const float*)d_in[0];   // (8,32,224,224,3) f32
  const float* noise = (const float*)d_in[1];   // (4,766) f32
  const float* basis = (const float*)d_in[2];   // (4,3,3) f32
  float* out  = (float*)d_out;
  float* Mbuf = (float*)d_ws;                   // 256*9 floats scratch

  build_mats_v2<<<NFRAMES, 256, 0, stream>>>(noise, basis, Mbuf);
  warp_bilinear_kernel<<<NFRAMES * BLOCKS_PER_FRAME, 256, 0, stream>>>(x, Mbuf, out);
}

// Round 5
// 264.587 us; speedup vs baseline: 1.0430x; 1.0283x over previous
//
#include <hip/hip_runtime.h>
#include <math.h>

// Problem constants (B=8, F=32 -> 256 frames of 224x224x3 f32)
#define NFRAMES 256
#define NH 224
#define NW 224
#define NPIX (NH * NW)            // 50176
#define NOISE_LEN 766             // 3*L - 2
#define WIN_LEN 511               // 2*L - 1
#define BLOCKS_PER_FRAME (NPIX / 256)  // 196

// ---------------------------------------------------------------------------
// Kernel 1 (unchanged): one block per frame (256 blocks -> one per CU).
// ---------------------------------------------------------------------------
__global__ __launch_bounds__(256) void build_mats_v2(
    const float* __restrict__ noise,   // (4, 766)
    const float* __restrict__ basis,   // (4, 3, 3)
    float* __restrict__ Mout) {        // (256, 9)
  const int b = blockIdx.x;      // frame index
  const int t = threadIdx.x;
  const int j = t >> 6;          // noise row (wave id)
  const int lane = t & 63;

  __shared__ double wsh[WIN_LEN];
  __shared__ double vsh[4];

  // weights w[k] = 1.1^(255 - |k-255|), k = 0..510
  for (int k = t; k < WIN_LEN; k += 256) {
    int e = 255 - abs(k - 255);
    wsh[k] = pow(1.1, (double)e);
  }
  __syncthreads();

  // sum(w) closed form: sum_{e=0}^{254} 1.1^e + sum_{e=0}^{255} 1.1^e
  const double S = (pow(1.1, 255.0) - 1.0) * 10.0 + (pow(1.1, 256.0) - 1.0) * 10.0;

  // conv (valid) at position b for row j: sum_{k=0}^{510} n[j][b+k] * w[k]
  const float* row = noise + j * NOISE_LEN + b;
  const int k0 = lane * 8;
  double acc = 0.0;
  #pragma unroll
  for (int i = 0; i < 8; ++i) {
    const int k = k0 + i;
    if (k < WIN_LEN) acc = fma((double)row[k], wsh[k], acc);
  }
  #pragma unroll
  for (int off = 32; off > 0; off >>= 1) acc += __shfl_down(acc, off, 64);
  if (lane == 0) {
    const double v = acc / S;
    vsh[j] = v > 0.0 ? v : 0.0;   // relu
  }
  __syncthreads();

  if (t == 0) {
    const double wv0 = vsh[0], wv1 = vsh[1], wv2 = vsh[2], wv3 = vsh[3];
    const double swv = wv0 + wv1 + wv2 + wv3;
    double warp[9];
    #pragma unroll
    for (int e = 0; e < 9; ++e) {
      warp[e] = wv0 * (double)basis[0 * 9 + e] + wv1 * (double)basis[1 * 9 + e] +
                wv2 * (double)basis[2 * 9 + e] + wv3 * (double)basis[3 * 9 + e];
    }
    warp[0] += 4.0 - swv;
    warp[4] += 4.0 - swv;
    warp[8] += 4.0 - swv;

    // M = [S(h-1,w-1) @ T(.5,.5)] @ warp @ [T(-.5,-.5) @ S(1/(h-1),1/(w-1))]
    const double W1 = (double)(NW - 1);
    const double H1 = (double)(NH - 1);
    double T[9];
    #pragma unroll
    for (int c = 0; c < 3; ++c) {
      T[0 * 3 + c] = W1 * warp[0 * 3 + c] + 0.5 * W1 * warp[2 * 3 + c];
      T[1 * 3 + c] = H1 * warp[1 * 3 + c] + 0.5 * H1 * warp[2 * 3 + c];
      T[2 * 3 + c] = warp[2 * 3 + c];
    }
    float* Mo = Mout + b * 9;
    #pragma unroll
    for (int r = 0; r < 3; ++r) {
      Mo[r * 3 + 0] = (float)(T[r * 3 + 0] / W1);
      Mo[r * 3 + 1] = (float)(T[r * 3 + 1] / H1);
      Mo[r * 3 + 2] = (float)(-0.5 * T[r * 3 + 0] - 0.5 * T[r * 3 + 1] + T[r * 3 + 2]);
    }
  }
}

// ---------------------------------------------------------------------------
// Kernel 2 (v7): VALU-lean warp+bilinear. 1 px/thread (r2 structure).
// ISOLATED CHANGE vs r2-best (264.0 us): validity/clamp/weight VALU diet.
//  Theory: kernel is VALU-bound (~100 wave-ops/px * 2cyc * 784 waves/CU
//  ~= 70+ us, matching measured ~74; explains r2/r3/r4 all-null on the
//  memory side). This version cuts the validity+clamp+weight cluster
//  from ~28 to ~10 VALU ops/px:
//   - pre-clamp x0f to [-2,225] -> exact int cvt, no overflow UB
//   - validity = single unsigned compare per corner ((unsigned)i <= 223)
//   - clamped index = min(max(i,0),223) -> v_med3_i32 combine
//   - xi1/yi1 = re-med3(i0+1): differs from ref clamp only when its
//     weight is exactly 0 (invalid corner), so output is identical
//   - validity folded into 4 axis weights via cndmask; corner weights
//     are then 4 muls (was 12)
//  Kept: packed dwordx3 corner loads, scalar NT stores, no swizzle.
// ---------------------------------------------------------------------------
__global__ __launch_bounds__(256) void warp_bilinear_kernel(
    const float* __restrict__ x,     // (256, 224, 224, 3)
    const float* __restrict__ M,     // (256, 9)
    float* __restrict__ out) {       // (256, 224, 224, 3)
  const int bid = blockIdx.x;
  const int l = bid / BLOCKS_PER_FRAME;                      // frame (block-uniform)
  const int p = (bid - l * BLOCKS_PER_FRAME) * 256 + threadIdx.x;  // pixel in frame

  const float* Mp = M + l * 9;   // uniform -> scalar loads
  const float m00 = Mp[0], m01 = Mp[1], m02 = Mp[2];
  const float m10 = Mp[3], m11 = Mp[4], m12 = Mp[5];
  const float m20 = Mp[6], m21 = Mp[7], m22 = Mp[8];

  const int r = p / NW;
  const int c = p - r * NW;
  const float cf = (float)c, rf = (float)r;

  const float fx = fmaf(m00, cf, fmaf(m01, rf, m02));
  const float fy = fmaf(m10, cf, fmaf(m11, rf, m12));
  const float fz = fmaf(m20, cf, fmaf(m21, rf, m22));
  const float inv = __builtin_amdgcn_rcpf(fz);   // ~2^-22 rel err, in budget
  const float xs = fx * inv;
  const float ys = fy * inv;

  const float x0f = floorf(xs), y0f = floorf(ys);
  const float wx = xs - x0f, wy = ys - y0f;

  // Pre-clamp keeps cvt exact and in-range; [-2,225] preserves validity of
  // both corner tests (x0 in [0,223]; x1 valid iff x0 in [-1,222]).
  const float x0c = fminf(fmaxf(x0f, -2.0f), 225.0f);
  const float y0c = fminf(fmaxf(y0f, -2.0f), 225.0f);
  const int ix0 = (int)x0c, iy0 = (int)y0c;      // exact
  const int ix1 = ix0 + 1,  iy1 = iy0 + 1;

  const bool vx0 = (unsigned)ix0 <= (unsigned)(NW - 1);  // 0<=ix0<=223
  const bool vx1 = (unsigned)ix1 <= (unsigned)(NW - 1);
  const bool vy0 = (unsigned)iy0 <= (unsigned)(NH - 1);
  const bool vy1 = (unsigned)iy1 <= (unsigned)(NH - 1);

  const int xi0 = min(max(ix0, 0), NW - 1);      // v_med3_i32
  const int xi1 = min(max(ix1, 0), NW - 1);
  const int yi0 = min(max(iy0, 0), NH - 1);
  const int yi1 = min(max(iy1, 0), NH - 1);

  const float* img = x + (size_t)l * (NPIX * 3);
  const float* p00 = img + (yi0 * NW + xi0) * 3;
  const float* p01 = img + (yi0 * NW + xi1) * 3;
  const float* p10 = img + (yi1 * NW + xi0) * 3;
  const float* p11 = img + (yi1 * NW + xi1) * 3;

  // Packed 12-B corner fetches -> global_load_dwordx3 each.
  float q00[3], q01[3], q10[3], q11[3];
  __builtin_memcpy(q00, p00, 12);
  __builtin_memcpy(q01, p01, 12);
  __builtin_memcpy(q10, p10, 12);
  __builtin_memcpy(q11, p11, 12);

  // Axis weights with validity folded in (cndmask), then 4 corner muls.
  const float wxb = vx0 ? (1.0f - wx) : 0.0f;
  const float wxa = vx1 ? wx          : 0.0f;
  const float wyb = vy0 ? (1.0f - wy) : 0.0f;
  const float wya = vy1 ? wy          : 0.0f;
  const float w00 = wyb * wxb;
  const float w01 = wyb * wxa;
  const float w10 = wya * wxb;
  const float w11 = wya * wxa;

  const float o0 = w00 * q00[0] + w01 * q01[0] + w10 * q10[0] + w11 * q11[0];
  const float o1 = w00 * q00[1] + w01 * q01[1] + w10 * q10[1] + w11 * q11[1];
  const float o2 = w00 * q00[2] + w01 * q01[2] + w10 * q10[2] + w11 * q11[2];

  // Nontemporal: out is never re-read; keep L2/L3 for the gather set.
  float* op = out + ((size_t)l * NPIX + p) * 3;
  __builtin_nontemporal_store(o0, op + 0);
  __builtin_nontemporal_store(o1, op + 1);
  __builtin_nontemporal_store(o2, op + 2);
}

extern "C" void kernel_launch(void* const* d_in, const int* in_sizes, int n_in,
                              void* d_out, int out_size, void* d_ws, size_t ws_size,
                              hipStream_t stream) {
  (void)in_sizes; (void)n_in; (void)out_size; (void)ws_size;
  const float* x     = (const float*)d_in[0];   // (8,32,224,224,3) f32
  const float* noise = (const float*)d_in[1];   // (4,766) f32
  const float* basis = (const float*)d_in[2];   // (4,3,3) f32
  float* out  = (float*)d_out;
  float* Mbuf = (float*)d_ws;                   // 256*9 floats scratch

  build_mats_v2<<<NFRAMES, 256, 0, stream>>>(noise, basis, Mbuf);
  warp_bilinear_kernel<<<NFRAMES * BLOCKS_PER_FRAME, 256, 0, stream>>>(x, Mbuf, out);
}

// Round 6
// 260.941 us; speedup vs baseline: 1.0576x; 1.0140x over previous
//
#include <hip/hip_runtime.h>
#include <math.h>

// Problem constants (B=8, F=32 -> 256 frames of 224x224x3 f32)
#define NFRAMES 256
#define NH 224
#define NW 224
#define NPIX (NH * NW)            // 50176
#define NOISE_LEN 766             // 3*L - 2
#define WIN_LEN 511               // 2*L - 1
#define TILES_X 14                // 224 / 16
#define BLOCKS_PER_FRAME (TILES_X * TILES_X)  // 196 (16x16 tiles)

// ---------------------------------------------------------------------------
// Kernel 1 (unchanged): one block per frame (256 blocks -> one per CU).
// ---------------------------------------------------------------------------
__global__ __launch_bounds__(256) void build_mats_v2(
    const float* __restrict__ noise,   // (4, 766)
    const float* __restrict__ basis,   // (4, 3, 3)
    float* __restrict__ Mout) {        // (256, 9)
  const int b = blockIdx.x;      // frame index
  const int t = threadIdx.x;
  const int j = t >> 6;          // noise row (wave id)
  const int lane = t & 63;

  __shared__ double wsh[WIN_LEN];
  __shared__ double vsh[4];

  // weights w[k] = 1.1^(255 - |k-255|), k = 0..510
  for (int k = t; k < WIN_LEN; k += 256) {
    int e = 255 - abs(k - 255);
    wsh[k] = pow(1.1, (double)e);
  }
  __syncthreads();

  // sum(w) closed form: sum_{e=0}^{254} 1.1^e + sum_{e=0}^{255} 1.1^e
  const double S = (pow(1.1, 255.0) - 1.0) * 10.0 + (pow(1.1, 256.0) - 1.0) * 10.0;

  // conv (valid) at position b for row j: sum_{k=0}^{510} n[j][b+k] * w[k]
  const float* row = noise + j * NOISE_LEN + b;
  const int k0 = lane * 8;
  double acc = 0.0;
  #pragma unroll
  for (int i = 0; i < 8; ++i) {
    const int k = k0 + i;
    if (k < WIN_LEN) acc = fma((double)row[k], wsh[k], acc);
  }
  #pragma unroll
  for (int off = 32; off > 0; off >>= 1) acc += __shfl_down(acc, off, 64);
  if (lane == 0) {
    const double v = acc / S;
    vsh[j] = v > 0.0 ? v : 0.0;   // relu
  }
  __syncthreads();

  if (t == 0) {
    const double wv0 = vsh[0], wv1 = vsh[1], wv2 = vsh[2], wv3 = vsh[3];
    const double swv = wv0 + wv1 + wv2 + wv3;
    double warp[9];
    #pragma unroll
    for (int e = 0; e < 9; ++e) {
      warp[e] = wv0 * (double)basis[0 * 9 + e] + wv1 * (double)basis[1 * 9 + e] +
                wv2 * (double)basis[2 * 9 + e] + wv3 * (double)basis[3 * 9 + e];
    }
    warp[0] += 4.0 - swv;
    warp[4] += 4.0 - swv;
    warp[8] += 4.0 - swv;

    // M = [S(h-1,w-1) @ T(.5,.5)] @ warp @ [T(-.5,-.5) @ S(1/(h-1),1/(w-1))]
    const double W1 = (double)(NW - 1);
    const double H1 = (double)(NH - 1);
    double T[9];
    #pragma unroll
    for (int c = 0; c < 3; ++c) {
      T[0 * 3 + c] = W1 * warp[0 * 3 + c] + 0.5 * W1 * warp[2 * 3 + c];
      T[1 * 3 + c] = H1 * warp[1 * 3 + c] + 0.5 * H1 * warp[2 * 3 + c];
      T[2 * 3 + c] = warp[2 * 3 + c];
    }
    float* Mo = Mout + b * 9;
    #pragma unroll
    for (int r = 0; r < 3; ++r) {
      Mo[r * 3 + 0] = (float)(T[r * 3 + 0] / W1);
      Mo[r * 3 + 1] = (float)(T[r * 3 + 1] / H1);
      Mo[r * 3 + 2] = (float)(-0.5 * T[r * 3 + 0] - 0.5 * T[r * 3 + 1] + T[r * 3 + 2]);
    }
  }
}

// ---------------------------------------------------------------------------
// Kernel 2 (v8): 16x16-tile blocks.
// ISOLATED CHANGE vs r5/r2-best (264.0 us): block = 16x16 output tile
// (was 1x256 strip). Same grid size (50176 blocks x 256 thr).
//  Theory: all pipe-level levers are exhausted (r2 insts neutral, r3
//  locality negative, r4 MLP neutral, r5 VALU neutral); the remaining
//  24us over the ~50us BW floor must live in the gather ACCESS PATTERN.
//  A 1x256 strip under a strong projective warp has a long tilted source
//  segment: per-instruction line counts grow with tilt (up to ~40),
//  bottom-corner rows (p10/p11) are reused by a DIFFERENT block at a
//  different time, and DRAM sees a narrow diagonal sweep. A 16x16 tile's
//  source footprint is a compact ~3.5KB patch: L1-resident, corner-row
//  reuse is intra-block, ~12-16 lines/gather-inst independent of tilt,
//  blocked 2D DRAM order. Stores remain full-line coalesced (16-lane row
//  segments are 192B, 64B-aligned -> 3 whole lines each).
//  Kept: v7 VALU-lean validity/clamp, packed dwordx3 loads, NT stores.
// Validity matches reference: un-clipped corner tests, clip-then-truncate
// indices, zero fill outside.
// ---------------------------------------------------------------------------
__global__ __launch_bounds__(256) void warp_bilinear_kernel(
    const float* __restrict__ x,     // (256, 224, 224, 3)
    const float* __restrict__ M,     // (256, 9)
    float* __restrict__ out) {       // (256, 224, 224, 3)
  const int bid = blockIdx.x;
  const int l = bid / BLOCKS_PER_FRAME;            // frame (block-uniform)
  const int tile = bid - l * BLOCKS_PER_FRAME;
  const int tr = (tile / TILES_X) << 4;            // tile row origin
  const int tc = (tile - (tile / TILES_X) * TILES_X) << 4;  // tile col origin
  const int r = tr + (threadIdx.x >> 4);
  const int c = tc + (threadIdx.x & 15);
  const int p = r * NW + c;

  const float* Mp = M + l * 9;   // uniform -> scalar loads
  const float m00 = Mp[0], m01 = Mp[1], m02 = Mp[2];
  const float m10 = Mp[3], m11 = Mp[4], m12 = Mp[5];
  const float m20 = Mp[6], m21 = Mp[7], m22 = Mp[8];

  const float cf = (float)c, rf = (float)r;

  const float fx = fmaf(m00, cf, fmaf(m01, rf, m02));
  const float fy = fmaf(m10, cf, fmaf(m11, rf, m12));
  const float fz = fmaf(m20, cf, fmaf(m21, rf, m22));
  const float inv = __builtin_amdgcn_rcpf(fz);   // ~2^-22 rel err, in budget
  const float xs = fx * inv;
  const float ys = fy * inv;

  const float x0f = floorf(xs), y0f = floorf(ys);
  const float wx = xs - x0f, wy = ys - y0f;

  // Pre-clamp keeps cvt exact and in-range; [-2,225] preserves validity of
  // both corner tests (x0 in [0,223]; x1 valid iff x0 in [-1,222]).
  const float x0c = fminf(fmaxf(x0f, -2.0f), 225.0f);
  const float y0c = fminf(fmaxf(y0f, -2.0f), 225.0f);
  const int ix0 = (int)x0c, iy0 = (int)y0c;      // exact
  const int ix1 = ix0 + 1,  iy1 = iy0 + 1;

  const bool vx0 = (unsigned)ix0 <= (unsigned)(NW - 1);  // 0<=ix0<=223
  const bool vx1 = (unsigned)ix1 <= (unsigned)(NW - 1);
  const bool vy0 = (unsigned)iy0 <= (unsigned)(NH - 1);
  const bool vy1 = (unsigned)iy1 <= (unsigned)(NH - 1);

  const int xi0 = min(max(ix0, 0), NW - 1);      // v_med3_i32
  const int xi1 = min(max(ix1, 0), NW - 1);
  const int yi0 = min(max(iy0, 0), NH - 1);
  const int yi1 = min(max(iy1, 0), NH - 1);

  const float* img = x + (size_t)l * (NPIX * 3);
  const float* p00 = img + (yi0 * NW + xi0) * 3;
  const float* p01 = img + (yi0 * NW + xi1) * 3;
  const float* p10 = img + (yi1 * NW + xi0) * 3;
  const float* p11 = img + (yi1 * NW + xi1) * 3;

  // Packed 12-B corner fetches -> global_load_dwordx3 each.
  float q00[3], q01[3], q10[3], q11[3];
  __builtin_memcpy(q00, p00, 12);
  __builtin_memcpy(q01, p01, 12);
  __builtin_memcpy(q10, p10, 12);
  __builtin_memcpy(q11, p11, 12);

  // Axis weights with validity folded in (cndmask), then 4 corner muls.
  const float wxb = vx0 ? (1.0f - wx) : 0.0f;
  const float wxa = vx1 ? wx          : 0.0f;
  const float wyb = vy0 ? (1.0f - wy) : 0.0f;
  const float wya = vy1 ? wy          : 0.0f;
  const float w00 = wyb * wxb;
  const float w01 = wyb * wxa;
  const float w10 = wya * wxb;
  const float w11 = wya * wxa;

  const float o0 = w00 * q00[0] + w01 * q01[0] + w10 * q10[0] + w11 * q11[0];
  const float o1 = w00 * q00[1] + w01 * q01[1] + w10 * q10[1] + w11 * q11[1];
  const float o2 = w00 * q00[2] + w01 * q01[2] + w10 * q10[2] + w11 * q11[2];

  // Nontemporal: out is never re-read; keep L2/L3 for the gather set.
  float* op = out + ((size_t)l * NPIX + p) * 3;
  __builtin_nontemporal_store(o0, op + 0);
  __builtin_nontemporal_store(o1, op + 1);
  __builtin_nontemporal_store(o2, op + 2);
}

extern "C" void kernel_launch(void* const* d_in, const int* in_sizes, int n_in,
                              void* d_out, int out_size, void* d_ws, size_t ws_size,
                              hipStream_t stream) {
  (void)in_sizes; (void)n_in; (void)out_size; (void)ws_size;
  const float* x     = (const float*)d_in[0];   // (8,32,224,224,3) f32
  const float* noise = (const float*)d_in[1];   // (4,766) f32
  const float* basis = (const float*)d_in[2];   // (4,3,3) f32
  float* out  = (float*)d_out;
  float* Mbuf = (float*)d_ws;                   // 256*9 floats scratch

  build_mats_v2<<<NFRAMES, 256, 0, stream>>>(noise, basis, Mbuf);
  warp_bilinear_kernel<<<NFRAMES * BLOCKS_PER_FRAME, 256, 0, stream>>>(x, Mbuf, out);
}